// Round 2
// baseline (11704.282 us; speedup 1.0000x reference)
//
#include <hip/hip_runtime.h>
#include <math.h>

// HybridDecoder: 3x ConvTranspose1d(stride2,k3)+ELU+BN  ->  15-step GRU  -> 2 big output GEMMs
// B=1024 H=1024 IN=512 OUT=8192 T=15.  All fp32 this round (correctness baseline).
// jax conv_transpose('IOH', transpose_kernel=True) identity (derived from jax source):
//   y[n,o,t] = sum_{i, 2l+k=t} x[n,i,l] * W[o,i,k]   (W raw (H,H,3), dim0 = OUTPUT channel)

#define HD    1024
#define BATCH 1024
#define IND   512
#define OUTD  8192
#define TSTEPS 15
#define EPSV  1e-5f

// ---------------------------------------------------------------------------
// GEMM-NT:  C(MxN) = A1(MxK1)@B1^T (+ A2(MxK2)@B2^T) + bias, epilogue.
// A row-major lda, B row-major (N x K) ldb  (i.e. computing X @ W^T).
// EPI: 0 = +bias, 1 = +bias,ELU,BN, 2 = +bias,ReLU
// TILE in {64,128}; 256 threads; micro-tile 4x4 (64) or 8x8 split-halves (128).
// ---------------------------------------------------------------------------
template<int EPI, int TILE>
__launch_bounds__(256)
__global__ void gemm_nt(int K1,
    const float* __restrict__ A1, int lda1, const float* __restrict__ B1, int ldb1,
    int K2,
    const float* __restrict__ A2, int lda2, const float* __restrict__ B2, int ldb2,
    const float* __restrict__ bias,
    const float* __restrict__ bng, const float* __restrict__ bnb,
    const float* __restrict__ bnm, const float* __restrict__ bnv,
    float* __restrict__ C, int ldc)
{
    constexpr int KT = 16;
    constexpr int RH = TILE / 64;   // row halves
    constexpr int CH = TILE / 64;   // col halves
    constexpr int F4 = TILE / 64;   // float4 loads per thread per matrix per K-tile

    __shared__ __align__(16) float As[KT][TILE];
    __shared__ __align__(16) float Bs[KT][TILE];

    const int tid = threadIdx.x;
    const int tx = tid & 15;
    const int ty = (tid >> 4) & 15;
    const int bm = blockIdx.y * TILE;
    const int bn = blockIdx.x * TILE;

    const int lrow = (TILE == 64) ? (tid >> 2) : (tid & 127);
    const int lk0  = (TILE == 64) ? ((tid & 3) * 4) : ((tid >> 7) * 8);

    float acc[4 * RH][4 * CH];
#pragma unroll
    for (int i = 0; i < 4 * RH; ++i)
#pragma unroll
        for (int j = 0; j < 4 * CH; ++j) acc[i][j] = 0.f;

    for (int pair = 0; pair < 2; ++pair) {
        const int K = pair ? K2 : K1;
        if (K == 0) continue;
        const float* __restrict__ A = pair ? A2 : A1;
        const float* __restrict__ B = pair ? B2 : B1;
        const int lda = pair ? lda2 : lda1;
        const int ldb = pair ? ldb2 : ldb1;
        const float* aptr = A + (size_t)(bm + lrow) * lda + lk0;
        const float* bptr = B + (size_t)(bn + lrow) * ldb + lk0;

        for (int k0 = 0; k0 < K; k0 += KT) {
            float4 av[F4], bv[F4];
#pragma unroll
            for (int f = 0; f < F4; ++f) {
                av[f] = *(const float4*)(aptr + k0 + f * 4);
                bv[f] = *(const float4*)(bptr + k0 + f * 4);
            }
            __syncthreads();   // previous compute done before overwriting LDS
#pragma unroll
            for (int f = 0; f < F4; ++f) {
                As[lk0 + f * 4 + 0][lrow] = av[f].x;
                As[lk0 + f * 4 + 1][lrow] = av[f].y;
                As[lk0 + f * 4 + 2][lrow] = av[f].z;
                As[lk0 + f * 4 + 3][lrow] = av[f].w;
                Bs[lk0 + f * 4 + 0][lrow] = bv[f].x;
                Bs[lk0 + f * 4 + 1][lrow] = bv[f].y;
                Bs[lk0 + f * 4 + 2][lrow] = bv[f].z;
                Bs[lk0 + f * 4 + 3][lrow] = bv[f].w;
            }
            __syncthreads();
#pragma unroll
            for (int k = 0; k < KT; ++k) {
                float a[4 * RH], b[4 * CH];
#pragma unroll
                for (int h = 0; h < RH; ++h) {
                    float4 t = *(const float4*)&As[k][h * 64 + ty * 4];
                    a[h * 4 + 0] = t.x; a[h * 4 + 1] = t.y;
                    a[h * 4 + 2] = t.z; a[h * 4 + 3] = t.w;
                }
#pragma unroll
                for (int h = 0; h < CH; ++h) {
                    float4 t = *(const float4*)&Bs[k][h * 64 + tx * 4];
                    b[h * 4 + 0] = t.x; b[h * 4 + 1] = t.y;
                    b[h * 4 + 2] = t.z; b[h * 4 + 3] = t.w;
                }
#pragma unroll
                for (int i = 0; i < 4 * RH; ++i)
#pragma unroll
                    for (int j = 0; j < 4 * CH; ++j)
                        acc[i][j] = fmaf(a[i], b[j], acc[i][j]);
            }
        }
    }

    // epilogue
#pragma unroll
    for (int i = 0; i < 4 * RH; ++i) {
        const int row = bm + (i >> 2) * 64 + ty * 4 + (i & 3);
#pragma unroll
        for (int h = 0; h < CH; ++h) {
            const int col0 = bn + h * 64 + tx * 4;
            float4 o;
            float* op = &o.x;
#pragma unroll
            for (int j = 0; j < 4; ++j) {
                const int col = col0 + j;
                float v = acc[i][h * 4 + j] + (bias ? bias[col] : 0.f);
                if (EPI == 1) {
                    float e = v > 0.f ? v : expm1f(v);          // ELU
                    float sc = bng[col] * rsqrtf(bnv[col] + EPSV);
                    v = (e - bnm[col]) * sc + bnb[col];          // BN (running stats)
                } else if (EPI == 2) {
                    v = fmaxf(v, 0.f);                           // ReLU
                }
                op[j] = v;
            }
            *(float4*)&C[(size_t)row * ldc + col0] = o;
        }
    }
}

// ---------------------------------------------------------------------------
// Pack conv weight (H,H,3) raw [o,i,k] -> (3,H,H) [k][o][i]  (K-major rows for GEMM B)
// NOTE: dim0 of the raw weight is the conv-transpose OUTPUT channel (jax 'IOH'
// + transpose_kernel=True semantics), so this is a pure strided gather.
// ---------------------------------------------------------------------------
__global__ void pack_w(const float* __restrict__ cw, float* __restrict__ wp)
{
    __shared__ float lds[768];
    const int o = blockIdx.x;           // output channel = raw dim0
    const int t = threadIdx.x;          // 256 threads
    const float* src = cw + (size_t)o * (HD * 3);
    for (int i0 = 0; i0 < HD; i0 += 256) {
#pragma unroll
        for (int r = 0; r < 3; ++r)
            lds[t + 256 * r] = src[i0 * 3 + t + 256 * r];
        __syncthreads();
#pragma unroll
        for (int k = 0; k < 3; ++k)
            wp[(size_t)k * HD * HD + (size_t)o * HD + i0 + t] = lds[t * 3 + k];
        __syncthreads();
    }
}

// ---------------------------------------------------------------------------
// GRU cell pointwise: r,z,n gates -> h_new.  gi/gh are (B, 3H).
// ---------------------------------------------------------------------------
__global__ void gru_cell(const float* __restrict__ gi, const float* __restrict__ gh,
                         const float* __restrict__ h_prev, float* __restrict__ h_out)
{
    const int idx = blockIdx.x * blockDim.x + threadIdx.x;   // < BATCH*HD
    const int n = idx >> 10, o = idx & 1023;
    const size_t base = (size_t)n * 3 * HD + o;
    const float ir = gi[base], iz = gi[base + HD], in_ = gi[base + 2 * HD];
    const float hr = gh[base], hz = gh[base + HD], hn = gh[base + 2 * HD];
    const float r  = 1.f / (1.f + expf(-(ir + hr)));
    const float zg = 1.f / (1.f + expf(-(iz + hz)));
    const float nn = tanhf(in_ + r * hn);
    h_out[idx] = (1.f - zg) * nn + zg * h_prev[idx];
}

__global__ void fill_const(float* __restrict__ p, float v, int n)
{
    const int i = blockIdx.x * blockDim.x + threadIdx.x;
    if (i < n) p[i] = v;
}

// ---------------------------------------------------------------------------
extern "C" void kernel_launch(void* const* d_in, const int* in_sizes, int n_in,
                              void* d_out, int out_size, void* d_ws, size_t ws_size,
                              hipStream_t stream)
{
    (void)in_sizes; (void)n_in; (void)out_size; (void)ws_size;

    const float* z    = (const float*)d_in[0];
    // d_in[1] = input_length (==15, compile-time T)
    const float* cw1  = (const float*)d_in[2];
    const float* cb1  = (const float*)d_in[3];
    const float* cw2  = (const float*)d_in[4];
    const float* cb2  = (const float*)d_in[5];
    const float* cw3  = (const float*)d_in[6];
    const float* cb3  = (const float*)d_in[7];
    const float* bn1g = (const float*)d_in[8];
    const float* bn1b = (const float*)d_in[9];
    const float* bn1m = (const float*)d_in[10];
    const float* bn1v = (const float*)d_in[11];
    const float* bn2g = (const float*)d_in[12];
    const float* bn2b = (const float*)d_in[13];
    const float* bn2m = (const float*)d_in[14];
    const float* bn2v = (const float*)d_in[15];
    const float* w_ih = (const float*)d_in[16];   // (3H, IN+H)
    const float* w_hh = (const float*)d_in[17];   // (3H, H)
    const float* b_ih = (const float*)d_in[18];
    const float* b_hh = (const float*)d_in[19];
    const float* h2xw = (const float*)d_in[20];   // (IN, H)
    const float* h2xb = (const float*)d_in[21];
    const float* d2ow = (const float*)d_in[22];   // (OUT, H)
    const float* d2ob = (const float*)d_in[23];
    const float* outw = (const float*)d_in[24];   // (OUT, H)
    const float* outb = (const float*)d_in[25];

    const size_t HH = (size_t)HD * HD;      // 1M
    const size_t BH = (size_t)BATCH * HD;   // 1M

    // workspace layout (floats); gi/gh/inp alias the packed-weight buffers
    // (weights only needed during the conv stages, which finish first). ~196 MB.
    float* ws   = (float*)d_ws;
    float* wp1  = ws;                  // 3*HH
    float* wp2  = wp1 + 3 * HH;        // 3*HH
    float* wp3  = wp2 + 3 * HH;        // 3*HH
    float* deca = wp3 + 3 * HH;        // 3*BH   (L,B,H) after stage1
    float* decb = deca + 3 * BH;       // 7*BH   after stage2
    float* dec3 = decb + 7 * BH;       // 15*BH  == dec_tbh (T,B,H)
    float* hs   = dec3 + 15 * BH;      // 15*BH  GRU hidden history
    float* gi   = wp1;                 // 3*BH alias
    float* gh   = wp2;                 // 3*BH alias
    float* inp  = wp3;                 // BATCH*IND alias

    pack_w<<<HD, 256, 0, stream>>>(cw1, wp1);
    pack_w<<<HD, 256, 0, stream>>>(cw2, wp2);
    pack_w<<<HD, 256, 0, stream>>>(cw3, wp3);

    const dim3 gHH(HD / 64, BATCH / 64);          // 1024x1024 GEMMs

    // stage 1: L=1 -> 3, single (l=0,k=t) pair each; epilogue ELU+BN1
    for (int t = 0; t < 3; ++t)
        gemm_nt<1, 64><<<gHH, 256, 0, stream>>>(
            HD, z, HD, wp1 + (size_t)t * HH, HD,
            0, nullptr, 0, nullptr, 0,
            cb1, bn1g, bn1b, bn1m, bn1v, deca + (size_t)t * BH, HD);

    // stage 2: L=3 -> 7; 1-2 (l,k) pairs per t; epilogue ELU+BN2
    for (int t = 0; t < 7; ++t) {
        int l0 = -1, k0 = 0, l1 = -1, k1 = 0, cnt = 0;
        for (int l = 0; l < 3; ++l) {
            int k = t - 2 * l;
            if (k >= 0 && k < 3) { if (cnt == 0) { l0 = l; k0 = k; } else { l1 = l; k1 = k; } ++cnt; }
        }
        gemm_nt<1, 64><<<gHH, 256, 0, stream>>>(
            HD, deca + (size_t)l0 * BH, HD, wp2 + (size_t)k0 * HH, HD,
            cnt > 1 ? HD : 0, cnt > 1 ? deca + (size_t)l1 * BH : nullptr, HD,
            cnt > 1 ? wp2 + (size_t)k1 * HH : nullptr, HD,
            cb2, bn2g, bn2b, bn2m, bn2v, decb + (size_t)t * BH, HD);
    }

    // stage 3: L=7 -> 15; bias only, output directly in (T,B,H)
    for (int t = 0; t < TSTEPS; ++t) {
        int l0 = -1, k0 = 0, l1 = -1, k1 = 0, cnt = 0;
        for (int l = 0; l < 7; ++l) {
            int k = t - 2 * l;
            if (k >= 0 && k < 3) { if (cnt == 0) { l0 = l; k0 = k; } else { l1 = l; k1 = k; } ++cnt; }
        }
        gemm_nt<0, 64><<<gHH, 256, 0, stream>>>(
            HD, decb + (size_t)l0 * BH, HD, wp3 + (size_t)k0 * HH, HD,
            cnt > 1 ? HD : 0, cnt > 1 ? decb + (size_t)l1 * BH : nullptr, HD,
            cnt > 1 ? wp3 + (size_t)k1 * HH : nullptr, HD,
            cb3, nullptr, nullptr, nullptr, nullptr, dec3 + (size_t)t * BH, HD);
    }

    // GRU: inp0 = full(OUT-2); h0 = z
    fill_const<<<(BATCH * IND) / 256, 256, 0, stream>>>(inp, (float)(OUTD - 2), BATCH * IND);

    const dim3 gGI(3 * HD / 64, BATCH / 64);
    const dim3 gIN(IND / 64, BATCH / 64);
    for (int t = 0; t < TSTEPS; ++t) {
        const float* dect = dec3 + (size_t)t * BH;
        const float* hp   = t ? hs + (size_t)(t - 1) * BH : z;
        float* hn = hs + (size_t)t * BH;
        // gi = [inp, dec_t] @ w_ih^T + b_ih   (dual-pair, no concat materialization)
        gemm_nt<0, 64><<<gGI, 256, 0, stream>>>(
            IND, inp, IND, w_ih, IND + HD,
            HD, dect, HD, w_ih + IND, IND + HD,
            b_ih, nullptr, nullptr, nullptr, nullptr, gi, 3 * HD);
        // gh = h @ w_hh^T + b_hh
        gemm_nt<0, 64><<<gGI, 256, 0, stream>>>(
            HD, hp, HD, w_hh, HD,
            0, nullptr, 0, nullptr, 0,
            b_hh, nullptr, nullptr, nullptr, nullptr, gh, 3 * HD);
        gru_cell<<<(BATCH * HD) / 256, 256, 0, stream>>>(gi, gh, hp, hn);
        // inp = relu(h_new @ h2x_w^T + h2x_b)
        gemm_nt<2, 64><<<gIN, 256, 0, stream>>>(
            HD, hn, HD, h2xw, HD,
            0, nullptr, 0, nullptr, 0,
            h2xb, nullptr, nullptr, nullptr, nullptr, inp, IND);
    }

    // output projections (the big ones): (15360 x 8192 x 1024) each
    float* out0 = (float*)d_out;
    float* out1 = out0 + (size_t)TSTEPS * BATCH * OUTD;
    const dim3 gOUT(OUTD / 128, TSTEPS * BATCH / 128);
    gemm_nt<0, 128><<<gOUT, 256, 0, stream>>>(
        HD, hs, HD, outw, HD,
        0, nullptr, 0, nullptr, 0,
        outb, nullptr, nullptr, nullptr, nullptr, out0, OUTD);
    gemm_nt<0, 128><<<gOUT, 256, 0, stream>>>(
        HD, dec3, HD, d2ow, HD,
        0, nullptr, 0, nullptr, 0,
        d2ob, nullptr, nullptr, nullptr, nullptr, out1, OUTD);
}

// Round 3
// 2193.547 us; speedup vs baseline: 5.3358x; 5.3358x over previous
//
#include <hip/hip_runtime.h>
#include <math.h>

// HybridDecoder, bf16-MFMA round. B=1024 H=1024 IN=512 OUT=8192 T=15.
// All GEMMs: C = A@B^T via mfma_f32_16x16x32_bf16, m97 structure
// (128x128 tile, BK=32, 4 waves of 4x4 16x16 frags, global_load_lds w=16).
// fp32 kept for: GRU cell state, gi/gh, biases/BN, final outputs.
// conv_transpose identity: y[n,o,t] = sum_{2l+k=t} x[n,i,l] * W[o,i,k]

#define HD    1024
#define BATCH 1024
#define IND   512
#define OUTD  8192
#define TSTEPS 15
#define EPSV  1e-5f

typedef unsigned short u16;
typedef __attribute__((ext_vector_type(8))) short bf16x8;
typedef __attribute__((ext_vector_type(8))) unsigned short u16x8;
typedef __attribute__((ext_vector_type(4))) float f32x4;

__device__ __forceinline__ u16 f2b(float f) {          // fp32 -> bf16 RNE
    union { float f; unsigned u; } x; x.f = f;
    unsigned r = x.u + 0x7fffu + ((x.u >> 16) & 1u);
    return (u16)(r >> 16);
}

typedef __attribute__((address_space(1))) const void gas_t;
typedef __attribute__((address_space(3))) void las_t;
__device__ __forceinline__ void gload_lds16(const u16* g, u16* l) {
    __builtin_amdgcn_global_load_lds((gas_t*)g, (las_t*)l, 16, 0, 0);
}

// ---------------------------------------------------------------------------
// 128x128 bf16 MFMA tile, dual K-pair (C = A1@B1^T + A2@B2^T + bias, epilogue)
// EPI: 0 none, 1 ELU+BN, 2 ReLU.  WF32/WB16: write fp32 / bf16 outputs.
// ---------------------------------------------------------------------------
template<int EPI, bool WF32, bool WB16>
__device__ __forceinline__ void gemm_tile(
    int bm, int bn,
    int K1, const u16* A1, int lda1, const u16* B1, int ldb1,
    int K2, const u16* A2, int lda2, const u16* B2, int ldb2,
    const float* bias,
    const float* bng, const float* bnb, const float* bnm, const float* bnv,
    float* Cf, u16* Cb, int ldc)
{
    __shared__ __align__(16) u16 As[128 * 32];
    __shared__ __align__(16) u16 Bs[128 * 32];

    const int tid  = threadIdx.x;
    const int lane = tid & 63;
    const int w    = tid >> 6;           // wave 0..3
    const int wr   = w >> 1, wc = w & 1; // wave quadrant (64x64)
    const int r_in = lane >> 2;          // staging row within 16-row group
    const int c_in = (lane & 3) * 8;     // staging k-chunk (8 bf16 = 16B)

    f32x4 acc[4][4];
#pragma unroll
    for (int m = 0; m < 4; ++m)
#pragma unroll
        for (int n = 0; n < 4; ++n) acc[m][n] = (f32x4){0.f, 0.f, 0.f, 0.f};

#pragma unroll 1
    for (int pair = 0; pair < 2; ++pair) {
        const int K = pair ? K2 : K1;
        if (K == 0) continue;
        const int lda = pair ? lda2 : lda1;
        const int ldb = pair ? ldb2 : ldb1;
        const u16* Ag = (pair ? A2 : A1) + (size_t)bm * lda;
        const u16* Bg = (pair ? B2 : B1) + (size_t)bn * ldb;

        for (int k0 = 0; k0 < K; k0 += 32) {
            // stage 128x32 A and B tiles; LDS dest = wave-uniform base (+lane*16 in HW)
#pragma unroll
            for (int i = 0; i < 2; ++i) {
                gload_lds16(Ag + (size_t)(i * 64 + w * 16 + r_in) * lda + k0 + c_in,
                            &As[i * 2048 + w * 512]);
                gload_lds16(Bg + (size_t)(i * 64 + w * 16 + r_in) * ldb + k0 + c_in,
                            &Bs[i * 2048 + w * 512]);
            }
            __syncthreads();   // drains vmcnt -> staged data visible

            const int fr = lane & 15;
            const int fk = (lane >> 4) * 8;
            bf16x8 av[4], bv[4];
#pragma unroll
            for (int m = 0; m < 4; ++m)
                av[m] = *(const bf16x8*)&As[(wr * 64 + m * 16 + fr) * 32 + fk];
#pragma unroll
            for (int n = 0; n < 4; ++n)
                bv[n] = *(const bf16x8*)&Bs[(wc * 64 + n * 16 + fr) * 32 + fk];
#pragma unroll
            for (int m = 0; m < 4; ++m)
#pragma unroll
                for (int n = 0; n < 4; ++n)
                    acc[m][n] = __builtin_amdgcn_mfma_f32_16x16x32_bf16(
                                    av[m], bv[n], acc[m][n], 0, 0, 0);
            __syncthreads();   // frag reads done before next-tile overwrite
        }
    }

    // epilogue: C/D layout col=lane&15, row=(lane>>4)*4+j  [m89-verified]
    const int col_l = lane & 15;
    const int row_h = (lane >> 4) * 4;
#pragma unroll
    for (int m = 0; m < 4; ++m) {
#pragma unroll
        for (int j = 0; j < 4; ++j) {
            const int row = bm + wr * 64 + m * 16 + row_h + j;
#pragma unroll
            for (int n = 0; n < 4; ++n) {
                const int col = bn + wc * 64 + n * 16 + col_l;
                float v = acc[m][n][j];
                if (bias) v += bias[col];
                if (EPI == 1) {
                    float e = v > 0.f ? v : expm1f(v);
                    float sc = bng[col] * rsqrtf(bnv[col] + EPSV);
                    v = (e - bnm[col]) * sc + bnb[col];
                } else if (EPI == 2) {
                    v = fmaxf(v, 0.f);
                }
                if (WF32) Cf[(size_t)row * ldc + col] = v;
                if (WB16) Cb[(size_t)row * ldc + col] = f2b(v);
            }
        }
    }
}

template<int EPI, bool WF32, bool WB16>
__launch_bounds__(256)
__global__ void gemm_nt(int K1, const u16* A1, int lda1, const u16* B1, int ldb1,
                        int K2, const u16* A2, int lda2, const u16* B2, int ldb2,
                        const float* bias,
                        const float* bng, const float* bnb, const float* bnm, const float* bnv,
                        float* Cf, u16* Cb, int ldc)
{
    gemm_tile<EPI, WF32, WB16>(blockIdx.y * 128, blockIdx.x * 128,
        K1, A1, lda1, B1, ldb1, K2, A2, lda2, B2, ldb2,
        bias, bng, bnb, bnm, bnv, Cf, Cb, ldc);
}

// conv stage batched over output time t = blockIdx.z; pairs from k = t - 2l
template<int EPI>
__launch_bounds__(256)
__global__ void conv_gemm(int Lin, const u16* X, const u16* W, const float* bias,
                          const float* bng, const float* bnb, const float* bnm, const float* bnv,
                          u16* Y)
{
    const int t = blockIdx.z;
    int l0 = 0, k0 = 0, l1 = 0, k1 = 0, cnt = 0;
    for (int l = 0; l < Lin; ++l) {
        int k = t - 2 * l;
        if (k >= 0 && k < 3) { if (!cnt) { l0 = l; k0 = k; } else { l1 = l; k1 = k; } ++cnt; }
    }
    const size_t BH = (size_t)BATCH * HD, HH = (size_t)HD * HD;
    gemm_tile<EPI, false, true>(blockIdx.y * 128, blockIdx.x * 128,
        HD, X + l0 * BH, HD, W + k0 * HH, HD,
        cnt > 1 ? HD : 0, X + l1 * BH, HD, W + k1 * HH, HD,
        bias, bng, bnb, bnm, bnv, nullptr, Y + (size_t)t * BH, HD);
}

// gi (z=0) and gh (z=1) in one launch; both N=3072
__launch_bounds__(256)
__global__ void gru_gemms(int K1gi, const u16* inp_b, const u16* w_ih_b,
                          const u16* dect, const u16* w_hh_b, const u16* h_b,
                          const float* bias_gi, const float* b_hh,
                          float* gi, float* gh)
{
    const bool z0 = (blockIdx.z == 0);
    gemm_tile<0, true, false>(blockIdx.y * 128, blockIdx.x * 128,
        z0 ? K1gi : HD, z0 ? inp_b : h_b, z0 ? IND : HD,
        z0 ? w_ih_b : w_hh_b, z0 ? (IND + HD) : HD,
        z0 ? HD : 0, dect, HD, w_ih_b + IND, IND + HD,
        z0 ? bias_gi : b_hh, nullptr, nullptr, nullptr, nullptr,
        z0 ? gi : gh, nullptr, 3 * HD);
}

// ---------------------------------------------------------------------------
__global__ void pack_w(const float* __restrict__ cw, u16* __restrict__ wp)
{   // (H,H,3) raw [o,i,k] -> bf16 (3,H,H) [k][o][i]
    __shared__ float lds[768];
    const int o = blockIdx.x, t = threadIdx.x;
    const float* src = cw + (size_t)o * (HD * 3);
    for (int i0 = 0; i0 < HD; i0 += 256) {
#pragma unroll
        for (int r = 0; r < 3; ++r) lds[t + 256 * r] = src[i0 * 3 + t + 256 * r];
        __syncthreads();
#pragma unroll
        for (int k = 0; k < 3; ++k)
            wp[(size_t)k * HD * HD + (size_t)o * HD + i0 + t] = f2b(lds[t * 3 + k]);
        __syncthreads();
    }
}

__global__ void f32_to_b16(const float* __restrict__ s, u16* __restrict__ d, int n)
{
    int i = (blockIdx.x * 256 + threadIdx.x) * 8;
    if (i >= n) return;
    float4 a = *(const float4*)(s + i);
    float4 b = *(const float4*)(s + i + 4);
    u16x8 o;
    o[0] = f2b(a.x); o[1] = f2b(a.y); o[2] = f2b(a.z); o[3] = f2b(a.w);
    o[4] = f2b(b.x); o[5] = f2b(b.y); o[6] = f2b(b.z); o[7] = f2b(b.w);
    *(u16x8*)(d + i) = o;
}

// bias0[j] = b_ih[j] + 8190 * sum_{k<IND} w_ih[j,k]   (exact fp32, kills the
// bf16-rounding of the constant inp0=8190 at t=0)
__global__ void bias0_k(const float* __restrict__ w_ih, const float* __restrict__ b_ih,
                        float* __restrict__ bias0)
{
    const int j = blockIdx.x, lane = threadIdx.x;   // 64 lanes
    float s = 0.f;
    for (int k = lane; k < IND; k += 64) s += w_ih[(size_t)j * (IND + HD) + k];
    for (int off = 32; off; off >>= 1) s += __shfl_down(s, off);
    if (lane == 0) bias0[j] = b_ih[j] + 8190.f * s;
}

__global__ void gru_cell(const float* __restrict__ gi, const float* __restrict__ gh,
                         const float* __restrict__ hp, float* __restrict__ ho,
                         u16* __restrict__ hb)
{
    const int idx = blockIdx.x * 256 + threadIdx.x;
    const int n = idx >> 10, o = idx & 1023;
    const size_t base = (size_t)n * 3 * HD + o;
    const float ir = gi[base], iz = gi[base + HD], in_ = gi[base + 2 * HD];
    const float hr = gh[base], hz = gh[base + HD], hn = gh[base + 2 * HD];
    const float r  = 1.f / (1.f + expf(-(ir + hr)));
    const float zg = 1.f / (1.f + expf(-(iz + hz)));
    const float nn = tanhf(in_ + r * hn);
    const float h  = (1.f - zg) * nn + zg * hp[idx];
    ho[idx] = h;
    hb[idx] = f2b(h);
}

// ---------------------------------------------------------------------------
extern "C" void kernel_launch(void* const* d_in, const int* in_sizes, int n_in,
                              void* d_out, int out_size, void* d_ws, size_t ws_size,
                              hipStream_t stream)
{
    (void)in_sizes; (void)n_in; (void)out_size; (void)ws_size;

    const float* z    = (const float*)d_in[0];
    const float* cw1  = (const float*)d_in[2];
    const float* cb1  = (const float*)d_in[3];
    const float* cw2  = (const float*)d_in[4];
    const float* cb2  = (const float*)d_in[5];
    const float* cw3  = (const float*)d_in[6];
    const float* cb3  = (const float*)d_in[7];
    const float* bn1g = (const float*)d_in[8];
    const float* bn1b = (const float*)d_in[9];
    const float* bn1m = (const float*)d_in[10];
    const float* bn1v = (const float*)d_in[11];
    const float* bn2g = (const float*)d_in[12];
    const float* bn2b = (const float*)d_in[13];
    const float* bn2m = (const float*)d_in[14];
    const float* bn2v = (const float*)d_in[15];
    const float* w_ih = (const float*)d_in[16];
    const float* w_hh = (const float*)d_in[17];
    const float* b_ih = (const float*)d_in[18];
    const float* b_hh = (const float*)d_in[19];
    const float* h2xw = (const float*)d_in[20];
    const float* h2xb = (const float*)d_in[21];
    const float* d2ow = (const float*)d_in[22];
    const float* d2ob = (const float*)d_in[23];
    const float* outw = (const float*)d_in[24];
    const float* outb = (const float*)d_in[25];

    const size_t HH = (size_t)HD * HD, BH = (size_t)BATCH * HD;

    // ---- workspace: bf16 region then fp32 region (~188 MB total) ----
    u16* wsb = (u16*)d_ws;
    size_t off = 0;
    auto A16 = [&](size_t n) { u16* p = wsb + off; off += n; return p; };
    u16* wp1   = A16(3 * HH);
    u16* wp2   = A16(3 * HH);
    u16* wp3   = A16(3 * HH);
    u16* wihb  = A16((size_t)3 * HD * (IND + HD));
    u16* whhb  = A16(3 * HH);
    u16* h2xbw = A16((size_t)IND * HD);
    u16* outwb = A16((size_t)OUTD * HD);
    u16* d2owb = A16((size_t)OUTD * HD);
    u16* zb    = A16(BH);
    u16* decab = A16(3 * BH);
    u16* decbb = A16(7 * BH);
    u16* dec3b = A16(15 * BH);
    u16* hsb   = A16(15 * BH);
    u16* inpb  = A16((size_t)BATCH * IND);
    float* wsf = (float*)(wsb + off);
    size_t foff = 0;
    auto A32 = [&](size_t n) { float* p = wsf + foff; foff += n; return p; };
    float* gi    = A32(3 * BH);
    float* gh    = A32(3 * BH);
    float* h0f   = A32(BH);
    float* h1f   = A32(BH);
    float* bias0 = A32(3 * HD);

    // ---- weight packing / bf16 conversion ----
    pack_w<<<HD, 256, 0, stream>>>(cw1, wp1);
    pack_w<<<HD, 256, 0, stream>>>(cw2, wp2);
    pack_w<<<HD, 256, 0, stream>>>(cw3, wp3);
    auto cvt = [&](const float* s, u16* d, size_t n) {
        f32_to_b16<<<(unsigned)(n / 2048), 256, 0, stream>>>(s, d, (int)n);
    };
    cvt(z, zb, BH);
    cvt(w_ih, wihb, (size_t)3 * HD * (IND + HD));
    cvt(w_hh, whhb, 3 * HH);
    cvt(h2xw, h2xbw, (size_t)IND * HD);
    cvt(outw, outwb, (size_t)OUTD * HD);
    cvt(d2ow, d2owb, (size_t)OUTD * HD);
    bias0_k<<<3 * HD, 64, 0, stream>>>(w_ih, b_ih, bias0);

    // ---- conv-transpose stages (batched over t) ----
    conv_gemm<1><<<dim3(8, 8, 3), 256, 0, stream>>>(1, zb, wp1, cb1,
        bn1g, bn1b, bn1m, bn1v, decab);
    conv_gemm<1><<<dim3(8, 8, 7), 256, 0, stream>>>(3, decab, wp2, cb2,
        bn2g, bn2b, bn2m, bn2v, decbb);
    conv_gemm<0><<<dim3(8, 8, 15), 256, 0, stream>>>(7, decbb, wp3, cb3,
        nullptr, nullptr, nullptr, nullptr, dec3b);

    // ---- GRU ----
    for (int t = 0; t < TSTEPS; ++t) {
        const u16* dect = dec3b + (size_t)t * BH;
        const u16* hb   = t ? hsb + (size_t)(t - 1) * BH : zb;
        const float* hpf = (t == 0) ? z : (((t - 1) & 1) ? h1f : h0f);
        float* hwf = (t & 1) ? h1f : h0f;
        gru_gemms<<<dim3(24, 8, 2), 256, 0, stream>>>(t ? IND : 0,
            inpb, wihb, dect, whhb, hb, t ? b_ih : bias0, b_hh, gi, gh);
        gru_cell<<<(BATCH * HD) / 256, 256, 0, stream>>>(gi, gh, hpf, hwf,
            hsb + (size_t)t * BH);
        if (t < TSTEPS - 1)
            gemm_nt<2, false, true><<<dim3(4, 8), 256, 0, stream>>>(
                HD, hsb + (size_t)t * BH, HD, h2xbw, HD,
                0, nullptr, 0, nullptr, 0,
                h2xb, nullptr, nullptr, nullptr, nullptr, nullptr, inpb, IND);
    }

    // ---- output projections ----
    float* out0 = (float*)d_out;
    float* out1 = out0 + (size_t)TSTEPS * BATCH * OUTD;
    gemm_nt<0, true, false><<<dim3(OUTD / 128, TSTEPS * BATCH / 128), 256, 0, stream>>>(
        HD, hsb, HD, outwb, HD, 0, nullptr, 0, nullptr, 0,
        outb, nullptr, nullptr, nullptr, nullptr, out0, nullptr, OUTD);
    gemm_nt<0, true, false><<<dim3(OUTD / 128, TSTEPS * BATCH / 128), 256, 0, stream>>>(
        HD, dec3b, HD, d2owb, HD, 0, nullptr, 0, nullptr, 0,
        d2ob, nullptr, nullptr, nullptr, nullptr, out1, nullptr, OUTD);
}

// Round 4
// 2144.074 us; speedup vs baseline: 5.4589x; 1.0231x over previous
//
#include <hip/hip_runtime.h>
#include <math.h>

// HybridDecoder. B=1024 H=1024 IN=512 OUT=8192 T=15.
// Round 4: projections moved to a 256x256 8-phase MFMA kernel (T1+T2+T3/T4+T5);
// conv/GRU keep the verified m97 128x128 structure from round 3.
// conv_transpose identity: y[n,o,t] = sum_{2l+k=t} x[n,i,l] * W[o,i,k]

#define HD    1024
#define BATCH 1024
#define IND   512
#define OUTD  8192
#define TSTEPS 15
#define EPSV  1e-5f

typedef unsigned short u16;
typedef __attribute__((ext_vector_type(8))) short bf16x8;
typedef __attribute__((ext_vector_type(8))) unsigned short u16x8;
typedef __attribute__((ext_vector_type(4))) float f32x4;

__device__ __forceinline__ u16 f2b(float f) {          // fp32 -> bf16 RNE
    union { float f; unsigned u; } x; x.f = f;
    unsigned r = x.u + 0x7fffu + ((x.u >> 16) & 1u);
    return (u16)(r >> 16);
}

typedef __attribute__((address_space(1))) const void gas_t;
typedef __attribute__((address_space(3))) void las_t;
__device__ __forceinline__ void gload_lds16(const u16* g, u16* l) {
    __builtin_amdgcn_global_load_lds((gas_t*)g, (las_t*)l, 16, 0, 0);
}

// ===========================================================================
// 256x256 8-phase GEMM (bf16 in, fp32 out):  C = A@B^T + bias
// 512 threads = 8 waves (2M x 4N); BK=64; LDS 128 KiB double-buffered.
// XOR-swizzled LDS (applied on global source + ds_read, per Guideline 21).
// Both projections in one dispatch via blockIdx.y.
// ===========================================================================
__launch_bounds__(512, 2)
__global__ void gemm256_dual(int nbn, int nk,
    const u16* __restrict__ A0, const u16* __restrict__ B0,
    const float* __restrict__ bias0, float* __restrict__ C0,
    const u16* __restrict__ A1, const u16* __restrict__ B1,
    const float* __restrict__ bias1, float* __restrict__ C1,
    int lda, int ldb, int ldc)
{
    const u16* A = blockIdx.y ? A1 : A0;
    const u16* B = blockIdx.y ? B1 : B0;
    const float* bias = blockIdx.y ? bias1 : bias0;
    float* C = blockIdx.y ? C1 : C0;

    // bijective XCD swizzle (m204)
    const int nwg = gridDim.x;
    const int q = nwg >> 3, r = nwg & 7;
    const int xcd = blockIdx.x & 7, idx = blockIdx.x >> 3;
    const int wg = (xcd < r ? xcd * (q + 1) : r * (q + 1) + (xcd - r) * q) + idx;
    const int bm = (wg / nbn) * 256;
    const int bn = (wg % nbn) * 256;

    __shared__ __align__(16) u16 As[2][256 * 64];
    __shared__ __align__(16) u16 Bs[2][256 * 64];

    const int tid = threadIdx.x;
    const int w   = tid >> 6;           // wave 0..7
    const int l   = tid & 63;
    const int wr  = w >> 2, wc = w & 3; // 2M x 4N wave grid
    const int srow = l >> 3;            // staging: row within 8-row chunk
    const int scb  = (l & 7) ^ srow;    // staging: swizzled source col-block
    const int fr   = l & 15;            // frag row
    const int fcb  = l >> 4;            // frag col-block base (0..3)
    const int swz  = l & 7;             // read-side xor (== row&7 of frag row)

    const u16* Ag = A + (size_t)bm * lda;
    const u16* Bg = B + (size_t)bn * ldb;

    auto stage = [&](int b, int kt) {   // stage K-tile kt into buffer b
        const int k0 = kt * 64 + scb * 8;
#pragma unroll
        for (int rr = 0; rr < 4; ++rr)
            gload_lds16(Ag + (size_t)(rr * 64 + w * 8 + srow) * lda + k0,
                        &As[b][(rr * 64 + w * 8) * 64]);
#pragma unroll
        for (int rr = 0; rr < 4; ++rr)
            gload_lds16(Bg + (size_t)(rr * 64 + w * 8 + srow) * ldb + k0,
                        &Bs[b][(rr * 64 + w * 8) * 64]);
    };

    f32x4 acc[8][4];
#pragma unroll
    for (int m = 0; m < 8; ++m)
#pragma unroll
        for (int n = 0; n < 4; ++n) acc[m][n] = (f32x4){0.f, 0.f, 0.f, 0.f};

    stage(0, 0);
    asm volatile("s_waitcnt vmcnt(0)" ::: "memory");
    asm volatile("s_barrier" ::: "memory");

    for (int kt = 0; kt < nk; ++kt) {
        const int cur = kt & 1;
#pragma unroll
        for (int ph = 0; ph < 4; ++ph) {
            const int mh = ph >> 1, nh = ph & 1;
            bf16x8 av[4][2], bv[2][2];
#pragma unroll
            for (int mm = 0; mm < 4; ++mm)
#pragma unroll
                for (int ks = 0; ks < 2; ++ks)
                    av[mm][ks] = *(const bf16x8*)&As[cur][
                        (wr * 128 + (mh * 4 + mm) * 16 + fr) * 64 +
                        (((ks * 4 + fcb) ^ swz) * 8)];
#pragma unroll
            for (int nn = 0; nn < 2; ++nn)
#pragma unroll
                for (int ks = 0; ks < 2; ++ks)
                    bv[nn][ks] = *(const bf16x8*)&Bs[cur][
                        (wc * 64 + (nh * 2 + nn) * 16 + fr) * 64 +
                        (((ks * 4 + fcb) ^ swz) * 8)];
            if (ph == 0 && kt + 1 < nk) stage(1 - cur, kt + 1);  // burst prefetch
            asm volatile("s_barrier" ::: "memory");
            __builtin_amdgcn_sched_barrier(0);
            __builtin_amdgcn_s_setprio(1);
#pragma unroll
            for (int mm = 0; mm < 4; ++mm)
#pragma unroll
                for (int nn = 0; nn < 2; ++nn)
#pragma unroll
                    for (int ks = 0; ks < 2; ++ks)
                        acc[mh * 4 + mm][nh * 2 + nn] =
                            __builtin_amdgcn_mfma_f32_16x16x32_bf16(
                                av[mm][ks], bv[nn][ks],
                                acc[mh * 4 + mm][nh * 2 + nn], 0, 0, 0);
            __builtin_amdgcn_s_setprio(0);
            __builtin_amdgcn_sched_barrier(0);
            if (ph == 3)   // prefetch issued 3 phases ago (~2500 cyc) -> ~free
                asm volatile("s_waitcnt vmcnt(0)" ::: "memory");
            asm volatile("s_barrier" ::: "memory");
        }
    }

    // epilogue: C/D layout col=lane&15, row=(lane>>4)*4+j
    const int row_h = (l >> 4) * 4;
#pragma unroll
    for (int m = 0; m < 8; ++m) {
#pragma unroll
        for (int j = 0; j < 4; ++j) {
            const int row = bm + wr * 128 + m * 16 + row_h + j;
#pragma unroll
            for (int n = 0; n < 4; ++n) {
                const int col = bn + wc * 64 + n * 16 + fr;
                C[(size_t)row * ldc + col] = acc[m][n][j] + bias[col];
            }
        }
    }
}

// ===========================================================================
// 128x128 m97-structure tile (verified round 3) for conv / GRU GEMMs
// ===========================================================================
template<int EPI, bool WF32, bool WB16>
__device__ __forceinline__ void gemm_tile(
    int bm, int bn,
    int K1, const u16* A1, int lda1, const u16* B1, int ldb1,
    int K2, const u16* A2, int lda2, const u16* B2, int ldb2,
    const float* bias,
    const float* bng, const float* bnb, const float* bnm, const float* bnv,
    float* Cf, u16* Cb, int ldc)
{
    __shared__ __align__(16) u16 As[128 * 32];
    __shared__ __align__(16) u16 Bs[128 * 32];

    const int tid  = threadIdx.x;
    const int lane = tid & 63;
    const int w    = tid >> 6;
    const int wr   = w >> 1, wc = w & 1;
    const int r_in = lane >> 2;
    const int c_in = (lane & 3) * 8;

    f32x4 acc[4][4];
#pragma unroll
    for (int m = 0; m < 4; ++m)
#pragma unroll
        for (int n = 0; n < 4; ++n) acc[m][n] = (f32x4){0.f, 0.f, 0.f, 0.f};

#pragma unroll 1
    for (int pair = 0; pair < 2; ++pair) {
        const int K = pair ? K2 : K1;
        if (K == 0) continue;
        const int lda = pair ? lda2 : lda1;
        const int ldb = pair ? ldb2 : ldb1;
        const u16* Ag = (pair ? A2 : A1) + (size_t)bm * lda;
        const u16* Bg = (pair ? B2 : B1) + (size_t)bn * ldb;

        for (int k0 = 0; k0 < K; k0 += 32) {
#pragma unroll
            for (int i = 0; i < 2; ++i) {
                gload_lds16(Ag + (size_t)(i * 64 + w * 16 + r_in) * lda + k0 + c_in,
                            &As[i * 2048 + w * 512]);
                gload_lds16(Bg + (size_t)(i * 64 + w * 16 + r_in) * ldb + k0 + c_in,
                            &Bs[i * 2048 + w * 512]);
            }
            __syncthreads();

            const int fr = lane & 15;
            const int fk = (lane >> 4) * 8;
            bf16x8 av[4], bv[4];
#pragma unroll
            for (int m = 0; m < 4; ++m)
                av[m] = *(const bf16x8*)&As[(wr * 64 + m * 16 + fr) * 32 + fk];
#pragma unroll
            for (int n = 0; n < 4; ++n)
                bv[n] = *(const bf16x8*)&Bs[(wc * 64 + n * 16 + fr) * 32 + fk];
#pragma unroll
            for (int m = 0; m < 4; ++m)
#pragma unroll
                for (int n = 0; n < 4; ++n)
                    acc[m][n] = __builtin_amdgcn_mfma_f32_16x16x32_bf16(
                                    av[m], bv[n], acc[m][n], 0, 0, 0);
            __syncthreads();
        }
    }

    const int col_l = lane & 15;
    const int row_h = (lane >> 4) * 4;
#pragma unroll
    for (int m = 0; m < 4; ++m) {
#pragma unroll
        for (int j = 0; j < 4; ++j) {
            const int row = bm + wr * 64 + m * 16 + row_h + j;
#pragma unroll
            for (int n = 0; n < 4; ++n) {
                const int col = bn + wc * 64 + n * 16 + col_l;
                float v = acc[m][n][j];
                if (bias) v += bias[col];
                if (EPI == 1) {
                    float e = v > 0.f ? v : expm1f(v);
                    float sc = bng[col] * rsqrtf(bnv[col] + EPSV);
                    v = (e - bnm[col]) * sc + bnb[col];
                } else if (EPI == 2) {
                    v = fmaxf(v, 0.f);
                }
                if (WF32) Cf[(size_t)row * ldc + col] = v;
                if (WB16) Cb[(size_t)row * ldc + col] = f2b(v);
            }
        }
    }
}

template<int EPI, bool WF32, bool WB16>
__launch_bounds__(256)
__global__ void gemm_nt(int K1, const u16* A1, int lda1, const u16* B1, int ldb1,
                        int K2, const u16* A2, int lda2, const u16* B2, int ldb2,
                        const float* bias,
                        const float* bng, const float* bnb, const float* bnm, const float* bnv,
                        float* Cf, u16* Cb, int ldc)
{
    gemm_tile<EPI, WF32, WB16>(blockIdx.y * 128, blockIdx.x * 128,
        K1, A1, lda1, B1, ldb1, K2, A2, lda2, B2, ldb2,
        bias, bng, bnb, bnm, bnv, Cf, Cb, ldc);
}

template<int EPI>
__launch_bounds__(256)
__global__ void conv_gemm(int Lin, const u16* X, const u16* W, const float* bias,
                          const float* bng, const float* bnb, const float* bnm, const float* bnv,
                          u16* Y)
{
    const int t = blockIdx.z;
    int l0 = 0, k0 = 0, l1 = 0, k1 = 0, cnt = 0;
    for (int l = 0; l < Lin; ++l) {
        int k = t - 2 * l;
        if (k >= 0 && k < 3) { if (!cnt) { l0 = l; k0 = k; } else { l1 = l; k1 = k; } ++cnt; }
    }
    const size_t BH = (size_t)BATCH * HD, HH = (size_t)HD * HD;
    gemm_tile<EPI, false, true>(blockIdx.y * 128, blockIdx.x * 128,
        HD, X + l0 * BH, HD, W + k0 * HH, HD,
        cnt > 1 ? HD : 0, X + l1 * BH, HD, W + k1 * HH, HD,
        bias, bng, bnb, bnm, bnv, nullptr, Y + (size_t)t * BH, HD);
}

__launch_bounds__(256)
__global__ void gru_gemms(int K1gi, const u16* inp_b, const u16* w_ih_b,
                          const u16* dect, const u16* w_hh_b, const u16* h_b,
                          const float* bias_gi, const float* b_hh,
                          float* gi, float* gh)
{
    const bool z0 = (blockIdx.z == 0);
    gemm_tile<0, true, false>(blockIdx.y * 128, blockIdx.x * 128,
        z0 ? K1gi : HD, z0 ? inp_b : h_b, z0 ? IND : HD,
        z0 ? w_ih_b : w_hh_b, z0 ? (IND + HD) : HD,
        z0 ? HD : 0, dect, HD, w_ih_b + IND, IND + HD,
        z0 ? bias_gi : b_hh, nullptr, nullptr, nullptr, nullptr,
        z0 ? gi : gh, nullptr, 3 * HD);
}

// ---------------------------------------------------------------------------
__global__ void pack_w(const float* __restrict__ cw, u16* __restrict__ wp)
{   // (H,H,3) raw [o,i,k] -> bf16 (3,H,H) [k][o][i]
    __shared__ float lds[768];
    const int o = blockIdx.x, t = threadIdx.x;
    const float* src = cw + (size_t)o * (HD * 3);
    for (int i0 = 0; i0 < HD; i0 += 256) {
#pragma unroll
        for (int r = 0; r < 3; ++r) lds[t + 256 * r] = src[i0 * 3 + t + 256 * r];
        __syncthreads();
#pragma unroll
        for (int k = 0; k < 3; ++k)
            wp[(size_t)k * HD * HD + (size_t)o * HD + i0 + t] = f2b(lds[t * 3 + k]);
        __syncthreads();
    }
}

__global__ void f32_to_b16(const float* __restrict__ s, u16* __restrict__ d, int n)
{
    int i = (blockIdx.x * 256 + threadIdx.x) * 8;
    if (i >= n) return;
    float4 a = *(const float4*)(s + i);
    float4 b = *(const float4*)(s + i + 4);
    u16x8 o;
    o[0] = f2b(a.x); o[1] = f2b(a.y); o[2] = f2b(a.z); o[3] = f2b(a.w);
    o[4] = f2b(b.x); o[5] = f2b(b.y); o[6] = f2b(b.z); o[7] = f2b(b.w);
    *(u16x8*)(d + i) = o;
}

__global__ void bias0_k(const float* __restrict__ w_ih, const float* __restrict__ b_ih,
                        float* __restrict__ bias0)
{
    const int j = blockIdx.x, lane = threadIdx.x;   // 64 lanes
    float s = 0.f;
    for (int k = lane; k < IND; k += 64) s += w_ih[(size_t)j * (IND + HD) + k];
    for (int off = 32; off; off >>= 1) s += __shfl_down(s, off);
    if (lane == 0) bias0[j] = b_ih[j] + 8190.f * s;
}

__global__ void gru_cell(const float* __restrict__ gi, const float* __restrict__ gh,
                         const float* __restrict__ hp, float* __restrict__ ho,
                         u16* __restrict__ hb)
{
    const int idx = blockIdx.x * 256 + threadIdx.x;
    const int n = idx >> 10, o = idx & 1023;
    const size_t base = (size_t)n * 3 * HD + o;
    const float ir = gi[base], iz = gi[base + HD], in_ = gi[base + 2 * HD];
    const float hr = gh[base], hz = gh[base + HD], hn = gh[base + 2 * HD];
    const float r  = 1.f / (1.f + expf(-(ir + hr)));
    const float zg = 1.f / (1.f + expf(-(iz + hz)));
    const float nn = tanhf(in_ + r * hn);
    const float h  = (1.f - zg) * nn + zg * hp[idx];
    ho[idx] = h;
    hb[idx] = f2b(h);
}

// ---------------------------------------------------------------------------
extern "C" void kernel_launch(void* const* d_in, const int* in_sizes, int n_in,
                              void* d_out, int out_size, void* d_ws, size_t ws_size,
                              hipStream_t stream)
{
    (void)in_sizes; (void)n_in; (void)out_size; (void)ws_size;

    const float* z    = (const float*)d_in[0];
    const float* cw1  = (const float*)d_in[2];
    const float* cb1  = (const float*)d_in[3];
    const float* cw2  = (const float*)d_in[4];
    const float* cb2  = (const float*)d_in[5];
    const float* cw3  = (const float*)d_in[6];
    const float* cb3  = (const float*)d_in[7];
    const float* bn1g = (const float*)d_in[8];
    const float* bn1b = (const float*)d_in[9];
    const float* bn1m = (const float*)d_in[10];
    const float* bn1v = (const float*)d_in[11];
    const float* bn2g = (const float*)d_in[12];
    const float* bn2b = (const float*)d_in[13];
    const float* bn2m = (const float*)d_in[14];
    const float* bn2v = (const float*)d_in[15];
    const float* w_ih = (const float*)d_in[16];
    const float* w_hh = (const float*)d_in[17];
    const float* b_ih = (const float*)d_in[18];
    const float* b_hh = (const float*)d_in[19];
    const float* h2xw = (const float*)d_in[20];
    const float* h2xb = (const float*)d_in[21];
    const float* d2ow = (const float*)d_in[22];
    const float* d2ob = (const float*)d_in[23];
    const float* outw = (const float*)d_in[24];
    const float* outb = (const float*)d_in[25];

    const size_t HH = (size_t)HD * HD, BH = (size_t)BATCH * HD;

    u16* wsb = (u16*)d_ws;
    size_t off = 0;
    auto A16 = [&](size_t n) { u16* p = wsb + off; off += n; return p; };
    u16* wp1   = A16(3 * HH);
    u16* wp2   = A16(3 * HH);
    u16* wp3   = A16(3 * HH);
    u16* wihb  = A16((size_t)3 * HD * (IND + HD));
    u16* whhb  = A16(3 * HH);
    u16* h2xbw = A16((size_t)IND * HD);
    u16* outwb = A16((size_t)OUTD * HD);
    u16* d2owb = A16((size_t)OUTD * HD);
    u16* zb    = A16(BH);
    u16* decab = A16(3 * BH);
    u16* decbb = A16(7 * BH);
    u16* dec3b = A16(15 * BH);
    u16* hsb   = A16(15 * BH);
    u16* inpb  = A16((size_t)BATCH * IND);
    float* wsf = (float*)(wsb + off);
    size_t foff = 0;
    auto A32 = [&](size_t n) { float* p = wsf + foff; foff += n; return p; };
    float* gi    = A32(3 * BH);
    float* gh    = A32(3 * BH);
    float* h0f   = A32(BH);
    float* h1f   = A32(BH);
    float* bias0 = A32(3 * HD);

    pack_w<<<HD, 256, 0, stream>>>(cw1, wp1);
    pack_w<<<HD, 256, 0, stream>>>(cw2, wp2);
    pack_w<<<HD, 256, 0, stream>>>(cw3, wp3);
    auto cvt = [&](const float* s, u16* d, size_t n) {
        f32_to_b16<<<(unsigned)(n / 2048), 256, 0, stream>>>(s, d, (int)n);
    };
    cvt(z, zb, BH);
    cvt(w_ih, wihb, (size_t)3 * HD * (IND + HD));
    cvt(w_hh, whhb, 3 * HH);
    cvt(h2xw, h2xbw, (size_t)IND * HD);
    cvt(outw, outwb, (size_t)OUTD * HD);
    cvt(d2ow, d2owb, (size_t)OUTD * HD);
    bias0_k<<<3 * HD, 64, 0, stream>>>(w_ih, b_ih, bias0);

    conv_gemm<1><<<dim3(8, 8, 3), 256, 0, stream>>>(1, zb, wp1, cb1,
        bn1g, bn1b, bn1m, bn1v, decab);
    conv_gemm<1><<<dim3(8, 8, 7), 256, 0, stream>>>(3, decab, wp2, cb2,
        bn2g, bn2b, bn2m, bn2v, decbb);
    conv_gemm<0><<<dim3(8, 8, 15), 256, 0, stream>>>(7, decbb, wp3, cb3,
        nullptr, nullptr, nullptr, nullptr, dec3b);

    fill_const:
    {
        // inp0 handled via bias0 at t=0; inpb only read for t>0 (K1gi=0 at t=0)
    }

    for (int t = 0; t < TSTEPS; ++t) {
        const u16* dect = dec3b + (size_t)t * BH;
        const u16* hb   = t ? hsb + (size_t)(t - 1) * BH : zb;
        const float* hpf = (t == 0) ? z : (((t - 1) & 1) ? h1f : h0f);
        float* hwf = (t & 1) ? h1f : h0f;
        gru_gemms<<<dim3(24, 8, 2), 256, 0, stream>>>(t ? IND : 0,
            inpb, wihb, dect, whhb, hb, t ? b_ih : bias0, b_hh, gi, gh);
        gru_cell<<<(BATCH * HD) / 256, 256, 0, stream>>>(gi, gh, hpf, hwf,
            hsb + (size_t)t * BH);
        if (t < TSTEPS - 1)
            gemm_nt<2, false, true><<<dim3(4, 8), 256, 0, stream>>>(
                HD, hsb + (size_t)t * BH, HD, h2xbw, HD,
                0, nullptr, 0, nullptr, 0,
                h2xb, nullptr, nullptr, nullptr, nullptr, nullptr, inpb, IND);
    }

    // output projections: one dual dispatch, 256^2 8-phase kernel
    float* out0 = (float*)d_out;
    float* out1 = out0 + (size_t)TSTEPS * BATCH * OUTD;
    const int nbm = (TSTEPS * BATCH) / 256, nbn = OUTD / 256;   // 60 x 32
    gemm256_dual<<<dim3(nbm * nbn, 2), 512, 0, stream>>>(nbn, HD / 64,
        hsb,   outwb, outb, out0,
        dec3b, d2owb, d2ob, out1,
        HD, HD, OUTD);
}